// Round 14
// baseline (314.080 us; speedup 1.0000x reference)
//
#include <hip/hip_runtime.h>
#include <math.h>

#define N_VOX 32768
#define N_EMB 8192
#define DIM 64
#define NCHUNK 8
#define CODES_PER_CHUNK (N_EMB / NCHUNK)       // 1024
#define TILES_PER_CHUNK (CODES_PER_CHUNK / 32) // 32
#define NTILES (N_EMB / 32)                    // 256
#define TILE_BYTES 8192                        // bh[4x1KB] | bl[4x1KB]
#define CHUNK_BYTES (TILES_PER_CHUNK * TILE_BYTES)
#define NRG (N_VOX / 256)                      // 128 row-groups

typedef _Float16 half8 __attribute__((ext_vector_type(8)));
typedef float floatx16 __attribute__((ext_vector_type(16)));

#define FP16_MIN_NORMAL 6.1035156e-5f
#define LO_SCALE 2048.0f

// -------- kernel A: fused esq + B-fragment stream build (validated R9-R13) ---
// 32x32x16 f16 B-frag per K-chunk o: lane l holds code n=l&31, k=o*16+(l>>5)*8+j.
// Tile (32 codes): [bh o=0..3 | bl o=0..3]; c0arr[code] = -1024*esq.
__global__ __launch_bounds__(64) void cbprep_kernel(const float* __restrict__ cb,
                                                    char* __restrict__ stream,
                                                    float* __restrict__ c0arr) {
    int l    = threadIdx.x;                      // 0..63
    int m    = l & 31;
    int kg   = l >> 5;
    int tile = blockIdx.x;                       // 0..255
    char* tbase = stream + (size_t)tile * TILE_BYTES;
    int code = tile * 32 + m;

    float ss = 0.f;
    #pragma unroll
    for (int o = 0; o < 4; ++o) {
        const float* p = cb + (size_t)code * DIM + o * 16 + kg * 8;
        half8 h, lo;
        #pragma unroll
        for (int j = 0; j < 8; ++j) {
            float x = p[j];
            ss = fmaf(x, x, ss);
            _Float16 hi = (_Float16)x;
            float hf = (float)hi;
            if (fabsf(hf) < FP16_MIN_NORMAL) { hi = (_Float16)0.f; hf = 0.f; }
            h[j]  = hi;
            lo[j] = (_Float16)((x - hf) * LO_SCALE);
        }
        *(half8*)(tbase +        o * 1024 + l * 16) = h;
        *(half8*)(tbase + 4096 + o * 1024 + l * 16) = lo;
    }
    ss += __shfl_xor(ss, 32, 64);                // both half-rows summed
    if (kg == 0)
        c0arr[code] = -1024.0f * ss;
}

// -------- kernel B: MFMA argmin scan + fused pick/gather/loss ---------------
// Main loop = validated R11/R13 (8 waves share 8KB LDS-dbuf tile). Epilogue:
// winner[row] = atomicMax of packed (orderable(score) << 32 | (8191-gid)) —
// float order == uint order after sign-flip; ties -> lowest gid (sequential
// semantics). The 8th chunk-block per row-group (device counter) gathers +
// writes quantized/index + loss partial; 128th finisher writes both losses.
// All cross-block reads are atomics (cross-XCD coherent, G16).
__global__ __launch_bounds__(512) void scan_kernel(const float* __restrict__ z,
                                                   const float* __restrict__ cb,
                                                   const char* __restrict__ stream,
                                                   const float* __restrict__ c0arr,
                                                   unsigned long long* __restrict__ winner,
                                                   unsigned int* __restrict__ rg_cnt,
                                                   float* __restrict__ loss_sum,
                                                   unsigned int* __restrict__ done_cnt,
                                                   float* __restrict__ out) {
    __shared__ __align__(16) char lds[2 * TILE_BYTES];
    __shared__ int lastFlag;
    int tid   = threadIdx.x;
    int l     = tid & 63;
    int w     = tid >> 6;                        // wave 0..7
    int chunk = blockIdx.x & (NCHUNK - 1);
    int rg    = blockIdx.x >> 3;                 // 0..127
    int m     = l & 31;
    int kg    = l >> 5;
    int rowBase = rg * 256 + w * 32;             // wave's 32 rows

    // A fragments: zh (unscaled), zl = 2048*res, zhs = 2048*zh (exact shift)
    half8 zh[4], zl[4], zhs[4];
    const float* zrow = z + (size_t)(rowBase + m) * DIM + kg * 8;
    #pragma unroll
    for (int o = 0; o < 4; ++o) {
        const float* p = zrow + o * 16;
        #pragma unroll
        for (int j = 0; j < 8; ++j) {
            float x = p[j];
            _Float16 hi = (_Float16)x;
            float hf = (float)hi;
            if (fabsf(hf) < FP16_MIN_NORMAL) { hi = (_Float16)0.f; hf = 0.f; }
            zh[o][j] = hi;
            zl[o][j] = (_Float16)((x - hf) * LO_SCALE);
        }
        zhs[o] = zh[o] * (_Float16)2048.0f;
    }

    const char*  sbase = stream + (size_t)chunk * CHUNK_BYTES;
    const float* c0p   = c0arr + chunk * CODES_PER_CHUNK;

    float best[16];
    int   bt[16];
    #pragma unroll
    for (int i = 0; i < 16; ++i) { best[i] = -3.4e38f; bt[i] = 0; }

    // stage one 8KB tile: wave w issues seg w (1KB, lane l -> +l*16)
#define STAGE(gt, lb)                                                              \
    do {                                                                           \
        const char* _g = (gt) + w * 1024 + l * 16;                                 \
        char*       _d = (lb) + w * 1024 + l * 16;                                 \
        __builtin_amdgcn_global_load_lds(                                          \
            (const __attribute__((address_space(1))) void*)_g,                     \
            (__attribute__((address_space(3))) void*)_d, 16, 0, 0);                \
    } while (0)

    STAGE(sbase, lds);                           // tile 0 -> buf 0
    float c0 = c0p[m];                           // tile 0's -1024*esq
    __syncthreads();                             // staging complete

    for (int t = 0; t < TILES_PER_CHUNK; ++t) {
        if (t + 1 < TILES_PER_CHUNK)
            STAGE(sbase + (size_t)(t + 1) * TILE_BYTES, lds + ((t + 1) & 1) * TILE_BYTES);
        float c0n = (t + 1 < TILES_PER_CHUNK) ? c0p[(t + 1) * 32 + m] : 0.f;

        const char* lb = lds + (t & 1) * TILE_BYTES;
        half8 bh[4], bl[4];
        #pragma unroll
        for (int o = 0; o < 4; ++o) {
            bh[o] = *(const half8*)(lb +        o * 1024 + l * 16);
            bl[o] = *(const half8*)(lb + 4096 + o * 1024 + l * 16);
        }

        floatx16 acc;
        #pragma unroll
        for (int i = 0; i < 16; ++i) acc[i] = c0;
        #pragma unroll
        for (int o = 0; o < 4; ++o) {
            acc = __builtin_amdgcn_mfma_f32_32x32x16_f16(zhs[o], bh[o], acc, 0, 0, 0);
            acc = __builtin_amdgcn_mfma_f32_32x32x16_f16(zl[o],  bh[o], acc, 0, 0, 0);
            acc = __builtin_amdgcn_mfma_f32_32x32x16_f16(zh[o],  bl[o], acc, 0, 0, 0);
        }
        #pragma unroll
        for (int i = 0; i < 16; ++i)
            if (acc[i] > best[i]) { best[i] = acc[i]; bt[i] = t; }

        c0 = c0n;
        __syncthreads();   // t+1 staging landed; all waves done reading buf t&1
    }
#undef STAGE

    // Cross-lane argmax (validated R8-R13 mapping), then packed atomicMax.
    #pragma unroll
    for (int i = 0; i < 16; ++i) {
        float v  = best[i];
        int   id = bt[i] * 32 + m;
        #pragma unroll
        for (int off = 1; off < 32; off <<= 1) {
            float ov = __shfl_xor(v, off, 64);
            int   oi = __shfl_xor(id, off, 64);
            if (ov > v || (ov == v && oi < id)) { v = ov; id = oi; }
        }
        if (m == 0) {
            int row = rowBase + (i & 3) + 8 * (i >> 2) + 4 * kg;
            int gid = chunk * CODES_PER_CHUNK + id;
            unsigned int ob = __float_as_uint(v);
            ob = (ob & 0x80000000u) ? ~ob : (ob | 0x80000000u);   // orderable
            unsigned long long key =
                ((unsigned long long)ob << 32) | (unsigned int)(8191 - gid);
            atomicMax(&winner[row], key);
        }
    }

    __threadfence();            // each wave drains its winner atomics
    __syncthreads();            // all waves of the block done
    if (tid == 0) {
        unsigned int old = atomicAdd(&rg_cnt[rg], 1u);
        lastFlag = (old == NCHUNK - 1) ? 1 : 0;
    }
    __syncthreads();

    if (lastFlag) {
        // All 8 chunks' winners for this rg are final. Gather + write + loss.
        int lane8 = tid & 7;       // dim segment (8 floats)
        int rsub  = tid >> 3;      // 0..63
        float ssacc = 0.f;
        #pragma unroll
        for (int pass = 0; pass < 4; ++pass) {
            int row = rg * 256 + pass * 64 + rsub;
            unsigned long long key = atomicMax(&winner[row], 0ULL); // coherent read
            int gid = 8191 - (int)(unsigned int)(key & 0xFFFFFFFFull);
            if (lane8 == 0)
                out[(size_t)N_VOX * DIM + 2 + row] = (float)gid;
            const float4* zp = (const float4*)(z  + (size_t)row * DIM + lane8 * 8);
            const float4* qp = (const float4*)(cb + (size_t)gid * DIM + lane8 * 8);
            float4*       op = (float4*)(out + (size_t)row * DIM + lane8 * 8);
            #pragma unroll
            for (int d2 = 0; d2 < 2; ++d2) {
                float4 zt = zp[d2], qt = qp[d2];
                float dx = qt.x - zt.x, dy = qt.y - zt.y;
                float dz = qt.z - zt.z, dw = qt.w - zt.w;
                float4 o;
                o.x = zt.x + dx; o.y = zt.y + dy;   // reference z + (q - z)
                o.z = zt.z + dz; o.w = zt.w + dw;
                op[d2] = o;
                ssacc += dx*dx + dy*dy + dz*dz + dw*dw;
            }
        }
        // block-reduce 512 partials in reused LDS
        float* sred = (float*)lds;
        sred[tid] = ssacc;
        __syncthreads();
        #pragma unroll
        for (int s = 256; s > 0; s >>= 1) {
            if (tid < s) sred[tid] += sred[tid + s];
            __syncthreads();
        }
        if (tid == 0) {
            atomicAdd(loss_sum, sred[0]);
            __threadfence();
            unsigned int d = atomicAdd(done_cnt, 1u);
            if (d == NRG - 1) {
                float tot = atomicAdd(loss_sum, 0.0f);   // coherent read-back
                float mean = tot / (float)((size_t)N_VOX * DIM);
                out[(size_t)N_VOX * DIM + 0] = mean;     // vq_loss
                out[(size_t)N_VOX * DIM + 1] = mean;     // commitment_loss
            }
        }
    }
}

extern "C" void kernel_launch(void* const* d_in, const int* in_sizes, int n_in,
                              void* d_out, int out_size, void* d_ws, size_t ws_size,
                              hipStream_t stream) {
    const float* z  = (const float*)d_in[0];   // [32768, 64]
    const float* cb = (const float*)d_in[1];   // [8192, 64]
    float* out = (float*)d_out;

    // ws: bstream [2 MB] | c0arr [32 KB] | winner [256 KB] | rg_cnt [512 B]
    //     | loss_sum [4 B] | done_cnt [4 B]
    char*  bstream  = (char*)d_ws;
    float* c0arr    = (float*)(bstream + (size_t)NTILES * TILE_BYTES);
    unsigned long long* winner = (unsigned long long*)(c0arr + N_EMB);
    unsigned int* rg_cnt   = (unsigned int*)(winner + N_VOX);
    float*        loss_sum = (float*)(rg_cnt + NRG);
    unsigned int* done_cnt = (unsigned int*)(loss_sum + 1);

    size_t zero_off = (size_t)NTILES * TILE_BYTES + (size_t)N_EMB * 4;
    size_t zero_sz  = (size_t)N_VOX * 8 + NRG * 4 + 4 + 4;
    hipMemsetAsync((char*)d_ws + zero_off, 0, zero_sz, stream);

    cbprep_kernel<<<dim3(NTILES), dim3(64), 0, stream>>>(cb, bstream, c0arr);
    scan_kernel  <<<dim3((N_VOX / 256) * NCHUNK), dim3(512), 0, stream>>>(
        z, cb, bstream, c0arr, winner, rg_cnt, loss_sum, done_cnt, out);
}